// Round 5
// baseline (233.637 us; speedup 1.0000x reference)
//
#include <hip/hip_runtime.h>
#include <hip/hip_bf16.h>
#include <math.h>

typedef unsigned int  uint;
typedef unsigned short ushort;

// Problem constants
#define DD    256      // embedding dim
#define KK    2048     // num codewords
#define HW    1024     // H*W
#define NN    32768    // rows
#define NUMEL 8388608  // total elements
#define STRIDEB (DD*HW)
#define NBLK_QL (NUMEL/1024)   // 8192 quant_loss blocks

// Workspace layout (bytes) — total ~2.64 MB
#define WS_H2     0         // 2048 f32: 0.5*||e_k||^2
#define WS_COUNTS 8192      // 2048 i32
#define WS_LOSS   16384     // (unused scratch, kept for layout stability)
#define WS_EBF    16512     // emb frag-ordered bf16 hi/lo: 2 MB
#define WS_PV     2113664   // 65536 f32 partial best value  (N x 2 halves)
#define WS_PI     2375808   // 65536 i32 partial best index
#define WS_BPART  WS_PV     // 8192 f32 (aliases pv; dead after merge)

// Output layout (floats): quantized_st | loss | perplexity | indices(as float)
#define OUT_LOSS  8388608
#define OUT_PPL   8388609
#define OUT_IDX   8388610

typedef __attribute__((ext_vector_type(8))) short  short8;   // 8 bf16 (4 VGPR)
typedef __attribute__((ext_vector_type(4))) float  float4v;  // 4 fp32 acc

__device__ __forceinline__ ushort f2bf(float f) {   // RNE fp32->bf16 bits
    uint u = __float_as_uint(f);
    return (ushort)((u + 0x7FFFu + ((u >> 16) & 1u)) >> 16);
}

// --------------------------------------------------------------------------
// Kernel 1: h2[k] = 0.5*sum_d emb[d][k]^2; zero the histogram.
__global__ __launch_bounds__(256) void e2h_kernel(const float* __restrict__ emb,
                                                  float* __restrict__ h2,
                                                  int*   __restrict__ counts) {
    int k = blockIdx.x * 256 + threadIdx.x;
    float s = 0.f;
    for (int d = 0; d < DD; ++d) {
        float v = emb[(size_t)d * KK + k];
        s += v * v;
    }
    h2[k] = 0.5f * s;
    counts[k] = 0;
}

// --------------------------------------------------------------------------
// Kernel 2: reorder emb (D,K) fp32 into MFMA-B-fragment-major bf16 hi/lo.
__global__ __launch_bounds__(256) void prep_emb(const float* __restrict__ emb,
                                                ushort* __restrict__ ebf) {
    int g  = blockIdx.x * 256 + threadIdx.x;
    int k  = g & (KK - 1);
    int dg = g >> 11;          // 0..31
    int d0 = dg * 8;
    int s    = dg >> 2;
    int quad = dg & 3;
    int ct   = k >> 4;
    int l    = quad * 16 + (k & 15);

    union { ushort us[8]; uint4 v; } hu, lu;
#pragma unroll
    for (int j = 0; j < 8; ++j) {
        float v = emb[(size_t)(d0 + j) * KK + k];
        ushort hb = f2bf(v);
        float  hf = __uint_as_float(((uint)hb) << 16);
        hu.us[j] = hb;
        lu.us[j] = f2bf(v - hf);
    }
    size_t hi_off = (size_t)(((ct * 8 + s) * 2 + 0) * 64 + l) * 8;
    size_t lo_off = (size_t)(((ct * 8 + s) * 2 + 1) * 64 + l) * 8;
    *(uint4*)(ebf + hi_off) = hu.v;
    *(uint4*)(ebf + lo_off) = lu.v;
}

// --------------------------------------------------------------------------
// Kernel 3: split-bf16 MFMA distance + per-row argmin over a column half.
// R5 restructure: double-buffered async B staging via global_load_lds(16B),
// ONE barrier per ct-iteration, h2 pre-staged to LDS so the loop body has no
// global ops besides the prefetch (a vmcnt wait on any global load would
// drain the prefetch queue — vmcnt waits are ordered).
__global__ __launch_bounds__(256, 2) void argmin_mfma(
    const float*  __restrict__ x,
    const ushort* __restrict__ ebf,
    const float*  __restrict__ h2,
    float* __restrict__ pv,
    int*   __restrict__ pi)
{
    __shared__ ushort sB[16384];  // 32 KB: two 16 KB B-tile buffers
    __shared__ float  sH[1024];   // 4 KB: h2 slice for this col-half

    const int tid  = threadIdx.x;
    const int w    = tid >> 6;
    const int lane = tid & 63;
    const int m    = lane & 15;
    const int quad = lane >> 4;

    const int rb = blockIdx.x >> 1;
    const int ch = blockIdx.x & 1;
    const int n0 = rb * 128 + w * 32;          // wave's first row
    const int b  = n0 >> 10;
    const int hwb = n0 & 1023;
    const float* xb = x + (size_t)b * STRIDEB;
    const int cbase = ch * 1024;
    const int ctg0  = cbase >> 4;

    // Async stage of one 16 KB B tile (ctg) into buffer bufsel.
    // LDS dest is wave-uniform base + lane*16 (HW scatter); our fragment
    // layout is exactly linear, so a linear copy is correct.
    auto stage = [&](int bufsel, int ctg) {
        const char* gb = (const char*)ebf + (size_t)ctg * 16384;
        char* lb = (char*)sB + (bufsel << 14);
#pragma unroll
        for (int i = 0; i < 4; ++i) {
            const int chunk = (w * 4 + i) << 10;
            __builtin_amdgcn_global_load_lds(
                (const __attribute__((address_space(1))) uint*)(gb + chunk + lane * 16),
                (__attribute__((address_space(3))) uint*)(lb + chunk),
                16, 0, 0);
        }
    };

    // Prologue: h2 slice -> LDS (1024 f32 = 256 lanes x 16 B)
    ((float4*)sH)[tid] = ((const float4*)(h2 + cbase))[tid];
    // Prefetch first B tile
    stage(0, ctg0);

    // A fragments in registers: 2 strips x 8 slices x (hi,lo).
    short8 xh[2][8], xl[2][8];
#pragma unroll
    for (int st = 0; st < 2; ++st) {
        const int hw = hwb + st * 16 + m;
#pragma unroll
        for (int s = 0; s < 8; ++s) {
            const float* p = xb + (size_t)(s * 32 + quad * 8) * HW + hw;
            short8 hh, ll;
#pragma unroll
            for (int j = 0; j < 8; ++j) {
                float v = p[(size_t)j * HW];
                v = fminf(fmaxf(v, -10.f), 10.f);
                ushort hb = f2bf(v);
                float  hf = __uint_as_float(((uint)hb) << 16);
                hh[j] = (short)hb;
                ll[j] = (short)f2bf(v - hf);
            }
            xh[st][s] = hh;
            xl[st][s] = ll;
        }
    }

    float bv[2][4] = {{1e30f,1e30f,1e30f,1e30f},{1e30f,1e30f,1e30f,1e30f}};
    int   bi[2][4] = {{0,0,0,0},{0,0,0,0}};

    for (int ct = 0; ct < 64; ++ct) {
        // Drains the staging of buffer (ct&1) [issued last iteration,
        // overlapped with that iteration's 48 MFMAs] and guarantees all
        // waves finished reading buffer ((ct+1)&1) before we restage it.
        __syncthreads();
        if (ct < 63) stage((ct + 1) & 1, ctg0 + ct + 1);

        const ushort* bufc = sB + ((ct & 1) << 13);
        float4v ahh0 = {0,0,0,0}, ahl0 = {0,0,0,0}, alh0 = {0,0,0,0};
        float4v ahh1 = {0,0,0,0}, ahl1 = {0,0,0,0}, alh1 = {0,0,0,0};
#pragma unroll
        for (int s = 0; s < 8; ++s) {
            short8 eh = *(const short8*)&bufc[(s * 2 + 0) * 512 + lane * 8];
            short8 el = *(const short8*)&bufc[(s * 2 + 1) * 512 + lane * 8];
            alh0 = __builtin_amdgcn_mfma_f32_16x16x32_bf16(xl[0][s], eh, alh0, 0, 0, 0);
            ahl0 = __builtin_amdgcn_mfma_f32_16x16x32_bf16(xh[0][s], el, ahl0, 0, 0, 0);
            ahh0 = __builtin_amdgcn_mfma_f32_16x16x32_bf16(xh[0][s], eh, ahh0, 0, 0, 0);
            alh1 = __builtin_amdgcn_mfma_f32_16x16x32_bf16(xl[1][s], eh, alh1, 0, 0, 0);
            ahl1 = __builtin_amdgcn_mfma_f32_16x16x32_bf16(xh[1][s], el, ahl1, 0, 0, 0);
            ahh1 = __builtin_amdgcn_mfma_f32_16x16x32_bf16(xh[1][s], eh, ahh1, 0, 0, 0);
        }
        const int c  = cbase + ct * 16 + m;
        const float hv = sH[ct * 16 + m];
#pragma unroll
        for (int i = 0; i < 4; ++i) {
            float s0 = hv - (ahh0[i] + (ahl0[i] + alh0[i]));
            float s1 = hv - (ahh1[i] + (ahl1[i] + alh1[i]));
            if (s0 < bv[0][i]) { bv[0][i] = s0; bi[0][i] = c; }
            if (s1 < bv[1][i]) { bv[1][i] = s1; bi[1][i] = c; }
        }
    }

    // Reduce across the 16 lanes of each quad (masks 8..1 stay inside).
#pragma unroll
    for (int st = 0; st < 2; ++st) {
#pragma unroll
        for (int i = 0; i < 4; ++i) {
            float v  = bv[st][i];
            int   ix = bi[st][i];
#pragma unroll
            for (int msk = 8; msk >= 1; msk >>= 1) {
                float ov = __shfl_xor(v, msk, 64);
                int   oi = __shfl_xor(ix, msk, 64);
                if (ov < v || (ov == v && oi < ix)) { v = ov; ix = oi; }
            }
            if (m == 0) {
                int n = n0 + st * 16 + quad * 4 + i;
                pv[n * 2 + ch] = v;
                pi[n * 2 + ch] = ix;
            }
        }
    }
}

// --------------------------------------------------------------------------
// Kernel 4: merge the two column halves; emit index + histogram.
__global__ __launch_bounds__(256) void merge_kernel(
    const float* __restrict__ pv, const int* __restrict__ pi,
    float* __restrict__ out_idx_f, int* __restrict__ counts)
{
    int n = blockIdx.x * 256 + threadIdx.x;
    float v0 = pv[n * 2 + 0], v1 = pv[n * 2 + 1];
    int   i0 = pi[n * 2 + 0], i1 = pi[n * 2 + 1];
    int ix = (v1 < v0) ? i1 : i0;
    ix = min(max(ix, 0), KK - 1);   // safety: bug -> wrong answer, not fault
    out_idx_f[n] = (float)ix;
    atomicAdd(&counts[ix], 1);
}

// --------------------------------------------------------------------------
// Kernel 5: gather quantized values + MSE reduction. No global atomics
// (R3 post-mortem: same-address float atomics = 420 us @ VALUBusy 1%).
__global__ __launch_bounds__(256) void quant_loss_kernel(
    const float* __restrict__ x,
    const float* __restrict__ emb,
    const float* __restrict__ idxf,
    float* __restrict__ outq,
    float* __restrict__ bpart)
{
    __shared__ float red[4];
    size_t o4 = ((size_t)blockIdx.x * 256 + threadIdx.x) * 4;
    int b  = (int)(o4 >> 18);
    int d  = (int)((o4 >> 10) & 255);
    int n  = b * HW + (int)(o4 & 1023);
    int i0 = (int)idxf[n + 0];
    int i1 = (int)idxf[n + 1];
    int i2 = (int)idxf[n + 2];
    int i3 = (int)idxf[n + 3];
    i0 = min(max(i0, 0), KK - 1); i1 = min(max(i1, 0), KK - 1);
    i2 = min(max(i2, 0), KK - 1); i3 = min(max(i3, 0), KK - 1);
    const float* er = emb + (size_t)d * KK;
    float4 q;
    q.x = er[i0]; q.y = er[i1]; q.z = er[i2]; q.w = er[i3];
    const float4 xv = *(const float4*)(x + o4);
    *(float4*)(outq + o4) = q;
    float ax = q.x - xv.x, ay = q.y - xv.y, az = q.z - xv.z, aw = q.w - xv.w;
    float s = ax * ax + ay * ay + az * az + aw * aw;
#pragma unroll
    for (int off = 32; off > 0; off >>= 1) s += __shfl_down(s, off, 64);
    if ((threadIdx.x & 63) == 0) red[threadIdx.x >> 6] = s;
    __syncthreads();
    if (threadIdx.x == 0)
        bpart[blockIdx.x] = red[0] + red[1] + red[2] + red[3];
}

// --------------------------------------------------------------------------
// Kernel 6: perplexity from histogram + loss from block partials.
__global__ __launch_bounds__(256) void finalize_kernel(
    const int* __restrict__ counts,
    const float* __restrict__ bpart,
    float* __restrict__ out)
{
    __shared__ float redp[4], redl[4];
    int tid = threadIdx.x;
    float s = 0.f;
    for (int k = tid; k < KK; k += 256) {
        float p = (float)counts[k] * (1.0f / (float)NN);
        s += p * logf(p + 1e-10f);
    }
    float ls = 0.f;
    for (int k = tid; k < NBLK_QL; k += 256) ls += bpart[k];
#pragma unroll
    for (int off = 32; off > 0; off >>= 1) {
        s  += __shfl_down(s, off, 64);
        ls += __shfl_down(ls, off, 64);
    }
    if ((tid & 63) == 0) { redp[tid >> 6] = s; redl[tid >> 6] = ls; }
    __syncthreads();
    if (tid == 0) {
        float tot = redp[0] + redp[1] + redp[2] + redp[3];
        float lsum = redl[0] + redl[1] + redl[2] + redl[3];
        out[OUT_PPL]  = expf(-tot);
        out[OUT_LOSS] = lsum * 1.25f / (float)NUMEL;
    }
}

// --------------------------------------------------------------------------
extern "C" void kernel_launch(void* const* d_in, const int* in_sizes, int n_in,
                              void* d_out, int out_size, void* d_ws, size_t ws_size,
                              hipStream_t stream) {
    const float* x   = (const float*)d_in[0];
    const float* emb = (const float*)d_in[1];
    float* out = (float*)d_out;
    char*  ws  = (char*)d_ws;

    float*  h2     = (float*)(ws + WS_H2);
    int*    counts = (int*)(ws + WS_COUNTS);
    ushort* ebf    = (ushort*)(ws + WS_EBF);
    float*  pv     = (float*)(ws + WS_PV);
    int*    pi     = (int*)(ws + WS_PI);
    float*  bpart  = (float*)(ws + WS_BPART);

    e2h_kernel<<<KK / 256, 256, 0, stream>>>(emb, h2, counts);
    prep_emb<<<256, 256, 0, stream>>>(emb, ebf);
    argmin_mfma<<<512, 256, 0, stream>>>(x, ebf, h2, pv, pi);
    merge_kernel<<<NN / 256, 256, 0, stream>>>(pv, pi, out + OUT_IDX, counts);
    quant_loss_kernel<<<NBLK_QL, 256, 0, stream>>>(x, emb, out + OUT_IDX, out, bpart);
    finalize_kernel<<<1, 256, 0, stream>>>(counts, bpart, out);
}